// Round 3
// baseline (777.772 us; speedup 1.0000x reference)
//
#include <hip/hip_runtime.h>

#define D 64
#define D4 (D / 4)         // 16 float4 per fp32 row
#define SBSHIFT 9          // 512 nodes per super-bucket
#define SBROWS 512
#define CHUNK_E 8192       // edges per chunk_sort block
#define NCH_MAX 256
#define NSB_MAX 256
#define PAD 65             // acc row stride in floats; 65 % 32 == 1 spreads banks by row

typedef float f32x4 __attribute__((ext_vector_type(4)));

__device__ __forceinline__ float elu1(float z) {
    return z > 0.0f ? z : expm1f(z);
}

// pack two fp32 -> bf16 pair (RNE), a in low 16, b in high 16
__device__ __forceinline__ unsigned int bfpair(float a, float b) {
    unsigned int ua = __float_as_uint(a);
    unsigned int ub = __float_as_uint(b);
    ua = (ua + 0x7FFFu + ((ua >> 16) & 1u)) >> 16;
    ub = (ub + 0x7FFFu + ((ub >> 16) & 1u)) & 0xFFFF0000u;
    return ub | ua;
}

__device__ __forceinline__ float bl16(int u) {
    return __uint_as_float((unsigned)u << 16);
}
__device__ __forceinline__ float bh16(int u) {
    return __uint_as_float((unsigned)u & 0xFFFF0000u);
}

// ---------- K1: emb16 = bf16(elu(x*w)); 32B/lane read, 16B/lane write ----------
__global__ void emb_kernel(const float* __restrict__ x,
                           const float* __restrict__ w,
                           uint4* __restrict__ emb16,
                           int total8) {
    int i = blockIdx.x * blockDim.x + threadIdx.x;
    if (i >= total8) return;
    f32x4 a = __builtin_nontemporal_load((const f32x4*)x + 2 * i);
    f32x4 b = __builtin_nontemporal_load((const f32x4*)x + 2 * i + 1);
    float4 wa = ((const float4*)w)[(2 * i) & 15];
    float4 wb = ((const float4*)w)[(2 * i + 1) & 15];
    uint4 o;
    o.x = bfpair(elu1(a.x * wa.x), elu1(a.y * wa.y));
    o.y = bfpair(elu1(a.z * wa.z), elu1(a.w * wa.w));
    o.z = bfpair(elu1(b.x * wb.x), elu1(b.y * wb.y));
    o.w = bfpair(elu1(b.z * wb.z), elu1(b.w * wb.w));
    emb16[i] = o;
}

// ---------- K2: per-chunk LDS bucket sort -> LINEAR coalesced flush + cbase ----
__global__ __launch_bounds__(512) void chunk_sort_kernel(
        const int* __restrict__ src, const int* __restrict__ dst,
        int* __restrict__ slots_lin,    // [NCH*CHUNK_E], pad-free
        int* __restrict__ cbase,        // [NCH][257] local run offsets
        int n_edges) {
    __shared__ int hist[256], base[256], cur[256];
    __shared__ int wsum[4];
    __shared__ int stage[CHUNK_E];      // 32 KB
    const int tid = threadIdx.x;
    const int lane = tid & 63, wid = tid >> 6;
    const int c0  = blockIdx.x * CHUNK_E;
    const int kn  = min(CHUNK_E, n_edges - c0);
    const int kn4 = kn >> 2;
    const int tail = kn & 3;

    if (tid < 256) hist[tid] = 0;
    __syncthreads();
    // pass 1: histogram by super-bucket (int4 loads)
    const int4* dst4 = (const int4*)(dst + c0);
    for (int k = tid; k < kn4; k += 512) {
        int4 dv = dst4[k];
        atomicAdd(&hist[dv.x >> SBSHIFT], 1);
        atomicAdd(&hist[dv.y >> SBSHIFT], 1);
        atomicAdd(&hist[dv.z >> SBSHIFT], 1);
        atomicAdd(&hist[dv.w >> SBSHIFT], 1);
    }
    if (tid < tail)
        atomicAdd(&hist[dst[c0 + (kn4 << 2) + tid] >> SBSHIFT], 1);
    __syncthreads();
    // exclusive scan of hist[0..256) on waves 0..3
    int h = 0, incl = 0;
    if (tid < 256) {
        h = hist[tid];
        incl = h;
        #pragma unroll
        for (int off = 1; off < 64; off <<= 1) {
            int t = __shfl_up(incl, off, 64);
            if (lane >= off) incl += t;
        }
        if (lane == 63) wsum[wid] = incl;
    }
    __syncthreads();
    if (tid < 256) {
        int pre = 0;
        for (int k = 0; k < wid; k++) pre += wsum[k];
        int e = pre + incl - h;
        base[tid] = e;
        cur[tid]  = e;
    }
    __syncthreads();
    // pass 2: scatter into LDS stage (edges L2-hot from pass 1)
    const int4* src4 = (const int4*)(src + c0);
    for (int k = tid; k < kn4; k += 512) {
        int4 dv = dst4[k];
        int4 sv = src4[k];
        int pos;
        pos = atomicAdd(&cur[dv.x >> SBSHIFT], 1);
        stage[pos] = ((dv.x & (SBROWS - 1)) << 17) | sv.x;
        pos = atomicAdd(&cur[dv.y >> SBSHIFT], 1);
        stage[pos] = ((dv.y & (SBROWS - 1)) << 17) | sv.y;
        pos = atomicAdd(&cur[dv.z >> SBSHIFT], 1);
        stage[pos] = ((dv.z & (SBROWS - 1)) << 17) | sv.z;
        pos = atomicAdd(&cur[dv.w >> SBSHIFT], 1);
        stage[pos] = ((dv.w & (SBROWS - 1)) << 17) | sv.w;
    }
    if (tid < tail) {
        int k = (kn4 << 2) + tid;
        int d = dst[c0 + k], s = src[c0 + k];
        int pos = atomicAdd(&cur[d >> SBSHIFT], 1);
        stage[pos] = ((d & (SBROWS - 1)) << 17) | s;
    }
    __syncthreads();
    // flush: fully coalesced linear copy, no padding, no partial lines
    for (int j = tid; j < kn; j += 512)
        slots_lin[c0 + j] = stage[j];
    if (tid < 256) cbase[blockIdx.x * 257 + tid] = base[tid];
    if (tid == 0)  cbase[blockIdx.x * 257 + 256] = kn;
}

// ---------- K3: per-super-bucket LDS fp32 accumulate (replaces fine sort +
//               gather).  One block per sb; acc[512][PAD] f32 in LDS; each
//               edge's bf16 row is gathered once and ds_add_f32'd into its
//               local row; flush coalesced.  No sorted2/node_off needed. ----
__global__ __launch_bounds__(512) void sb_accum_kernel(
        const unsigned int* __restrict__ emb16,
        const int* __restrict__ slots_lin,
        const int* __restrict__ cbase,
        float* __restrict__ out,
        int n_nodes, int NCH) {
    __shared__ int rstart[NCH_MAX], rc[NCH_MAX];
    __shared__ float acc[SBROWS * PAD];      // 133,120 B
    const int s = blockIdx.x;
    const int tid = threadIdx.x;             // 512
    const int wid = tid >> 6, lane = tid & 63;
    const int g = lane >> 3;                 // 8 edge slots per wave
    const int c = lane & 7;                  // 8 int4 chunks per 128B row

    if (tid < NCH) {
        int a = cbase[tid * 257 + s];
        int b = cbase[tid * 257 + s + 1];
        rstart[tid] = tid * CHUNK_E + a;
        rc[tid] = b - a;
    }
    for (int i = tid; i < SBROWS * PAD; i += 512) acc[i] = 0.0f;
    __syncthreads();

    const int4* row = (const int4*)emb16;    // 8 int4 per row
    for (int ch = wid; ch < NCH; ch += 8) {
        const int n = rc[ch], st = rstart[ch];
        int j = g;
        for (; j + 8 < n; j += 16) {
            int pl0 = slots_lin[st + j];
            int pl1 = slots_lin[st + j + 8];
            int s0 = pl0 & 0x1FFFF, s1 = pl1 & 0x1FFFF;
            int r0 = ((unsigned)pl0) >> 17, r1 = ((unsigned)pl1) >> 17;
            int4 u0 = row[s0 * 8 + c];
            int4 u1 = row[s1 * 8 + c];
            float* A0 = acc + r0 * PAD + c * 8;
            float* A1 = acc + r1 * PAD + c * 8;
            atomicAdd(A0 + 0, bl16(u0.x)); atomicAdd(A0 + 1, bh16(u0.x));
            atomicAdd(A0 + 2, bl16(u0.y)); atomicAdd(A0 + 3, bh16(u0.y));
            atomicAdd(A0 + 4, bl16(u0.z)); atomicAdd(A0 + 5, bh16(u0.z));
            atomicAdd(A0 + 6, bl16(u0.w)); atomicAdd(A0 + 7, bh16(u0.w));
            atomicAdd(A1 + 0, bl16(u1.x)); atomicAdd(A1 + 1, bh16(u1.x));
            atomicAdd(A1 + 2, bl16(u1.y)); atomicAdd(A1 + 3, bh16(u1.y));
            atomicAdd(A1 + 4, bl16(u1.z)); atomicAdd(A1 + 5, bh16(u1.z));
            atomicAdd(A1 + 6, bl16(u1.w)); atomicAdd(A1 + 7, bh16(u1.w));
        }
        if (j < n) {
            int pl0 = slots_lin[st + j];
            int s0 = pl0 & 0x1FFFF;
            int r0 = ((unsigned)pl0) >> 17;
            int4 u0 = row[s0 * 8 + c];
            float* A0 = acc + r0 * PAD + c * 8;
            atomicAdd(A0 + 0, bl16(u0.x)); atomicAdd(A0 + 1, bh16(u0.x));
            atomicAdd(A0 + 2, bl16(u0.y)); atomicAdd(A0 + 3, bh16(u0.y));
            atomicAdd(A0 + 4, bl16(u0.z)); atomicAdd(A0 + 5, bh16(u0.z));
            atomicAdd(A0 + 6, bl16(u0.w)); atomicAdd(A0 + 7, bh16(u0.w));
        }
    }
    __syncthreads();

    // flush: coalesced 16B stores via ext-vector f32x4 (nontemporal needs
    // scalar/ext-vector pointee, not HIP_vector_type)
    const int base = s << SBSHIFT;
    const int nv = min(SBROWS, n_nodes - base);
    f32x4* out4 = (f32x4*)out;
    for (int idx = tid; idx < nv * 16; idx += 512) {
        int r = idx >> 4, q = idx & 15;
        const float* A = acc + r * PAD + q * 4;
        f32x4 v = {A[0], A[1], A[2], A[3]};
        __builtin_nontemporal_store(v, out4 + (size_t)base * 16 + idx);
    }
}

// ---------- Fallback: atomic scatter ----------
__global__ void zero_out_kernel(float* __restrict__ out, int total4) {
    int i = blockIdx.x * blockDim.x + threadIdx.x;
    if (i < total4) ((float4*)out)[i] = make_float4(0.f, 0.f, 0.f, 0.f);
}

__global__ void scatter_fused_kernel(const float* __restrict__ x,
                                     const float* __restrict__ w,
                                     const int* __restrict__ src,
                                     const int* __restrict__ dst,
                                     float* __restrict__ out, int n_edges) {
    int t = blockIdx.x * blockDim.x + threadIdx.x;
    int e = t >> 4;
    int c = t & 15;
    if (e >= n_edges) return;
    int s = src[e];
    int d = dst[e];
    float4 xv = ((const float4*)x)[s * D4 + c];
    float4 wv = ((const float4*)w)[c];
    float* o = out + d * D + c * 4;
    unsafeAtomicAdd(o + 0, elu1(xv.x * wv.x));
    unsafeAtomicAdd(o + 1, elu1(xv.y * wv.y));
    unsafeAtomicAdd(o + 2, elu1(xv.z * wv.z));
    unsafeAtomicAdd(o + 3, elu1(xv.w * wv.w));
}

extern "C" void kernel_launch(void* const* d_in, const int* in_sizes, int n_in,
                              void* d_out, int out_size, void* d_ws, size_t ws_size,
                              hipStream_t stream) {
    const float* x   = (const float*)d_in[0];   // [N, 64] fp32
    const float* w   = (const float*)d_in[1];   // [1, 64] fp32
    const int*   src = (const int*)d_in[2];     // [E] int32
    const int*   dst = (const int*)d_in[3];     // [E] int32
    float* out = (float*)d_out;

    const int n_nodes = in_sizes[0] / D;
    const int n_edges = in_sizes[2];
    const int total4  = n_nodes * D4;
    const int total8  = n_nodes * 8;
    const int block = 256;

    const int NSB = (n_nodes + SBROWS - 1) >> SBSHIFT;
    const int NCH = (n_edges + CHUNK_E - 1) / CHUNK_E;

    auto align16 = [](size_t v) { return (v + 15) & ~size_t(15); };
    const size_t emb_b      = align16((size_t)n_nodes * D * 2);          // bf16
    const size_t slots_b    = align16((size_t)NCH * CHUNK_E * 4);
    const size_t cbase_b    = align16((size_t)NCH * 257 * 4);
    const size_t need = emb_b + slots_b + cbase_b;

    if (ws_size >= need && n_nodes <= 131072 && NSB <= NSB_MAX && NCH <= NCH_MAX) {
        char* p = (char*)d_ws;
        unsigned int* emb16 = (unsigned int*)p;  p += emb_b;
        int* slots_lin = (int*)p;  p += slots_b;
        int* cbase     = (int*)p;

        emb_kernel<<<(total8 + block - 1) / block, block, 0, stream>>>(
            x, w, (uint4*)emb16, total8);
        chunk_sort_kernel<<<NCH, 512, 0, stream>>>(
            src, dst, slots_lin, cbase, n_edges);
        sb_accum_kernel<<<NSB, 512, 0, stream>>>(
            emb16, slots_lin, cbase, out, n_nodes, NCH);
    } else {
        zero_out_kernel<<<(total4 + block - 1) / block, block, 0, stream>>>(out, total4);
        const int nt = n_edges * 16;
        scatter_fused_kernel<<<(nt + block - 1) / block, block, 0, stream>>>(
            x, w, src, dst, out, n_edges);
    }
}

// Round 4
// 155.863 us; speedup vs baseline: 4.9901x; 4.9901x over previous
//
#include <hip/hip_runtime.h>

#define D 64
#define D4 (D / 4)         // 16 float4 per fp32 row
#define SBSHIFT 9          // 512 nodes per super-bucket
#define SBROWS 512
#define CHUNK_E 8192       // edges per chunk_sort block
#define STAGE_CAP 8704     // fine_sort staging entries (mean ~8163, +6 sigma)
#define NCH_MAX 256
#define NSB_MAX 256

typedef float f32x4 __attribute__((ext_vector_type(4)));

__device__ __forceinline__ float elu1(float z) {
    return z > 0.0f ? z : expm1f(z);
}

// pack two fp32 -> bf16 pair (RNE), a in low 16, b in high 16
__device__ __forceinline__ unsigned int bfpair(float a, float b) {
    unsigned int ua = __float_as_uint(a);
    unsigned int ub = __float_as_uint(b);
    ua = (ua + 0x7FFFu + ((ua >> 16) & 1u)) >> 16;
    ub = (ub + 0x7FFFu + ((ub >> 16) & 1u)) & 0xFFFF0000u;
    return ub | ua;
}

__device__ __forceinline__ float bl16(int u) {
    return __uint_as_float((unsigned)u << 16);
}
__device__ __forceinline__ float bh16(int u) {
    return __uint_as_float((unsigned)u & 0xFFFF0000u);
}

// ---------- K1: emb16 = bf16(elu(x*w)); 32B/lane read, 16B/lane write ----------
__global__ void emb_kernel(const float* __restrict__ x,
                           const float* __restrict__ w,
                           uint4* __restrict__ emb16,
                           int total8) {
    int i = blockIdx.x * blockDim.x + threadIdx.x;
    if (i >= total8) return;
    f32x4 a = __builtin_nontemporal_load((const f32x4*)x + 2 * i);
    f32x4 b = __builtin_nontemporal_load((const f32x4*)x + 2 * i + 1);
    float4 wa = ((const float4*)w)[(2 * i) & 15];
    float4 wb = ((const float4*)w)[(2 * i + 1) & 15];
    uint4 o;
    o.x = bfpair(elu1(a.x * wa.x), elu1(a.y * wa.y));
    o.y = bfpair(elu1(a.z * wa.z), elu1(a.w * wa.w));
    o.z = bfpair(elu1(b.x * wb.x), elu1(b.y * wb.y));
    o.w = bfpair(elu1(b.z * wb.z), elu1(b.w * wb.w));
    emb16[i] = o;
}

// ---------- K2: per-chunk LDS bucket sort -> LINEAR coalesced flush + cbase ----
__global__ __launch_bounds__(512) void chunk_sort_kernel(
        const int* __restrict__ src, const int* __restrict__ dst,
        int* __restrict__ slots_lin,    // [NCH*CHUNK_E], pad-free
        int* __restrict__ cbase,        // [NCH][257] local run offsets
        int n_edges) {
    __shared__ int hist[256], base[256], cur[256];
    __shared__ int wsum[4];
    __shared__ int stage[CHUNK_E];      // 32 KB
    const int tid = threadIdx.x;
    const int lane = tid & 63, wid = tid >> 6;
    const int c0  = blockIdx.x * CHUNK_E;
    const int kn  = min(CHUNK_E, n_edges - c0);
    const int kn4 = kn >> 2;
    const int tail = kn & 3;

    if (tid < 256) hist[tid] = 0;
    __syncthreads();
    // pass 1: histogram by super-bucket (int4 loads)
    const int4* dst4 = (const int4*)(dst + c0);
    for (int k = tid; k < kn4; k += 512) {
        int4 dv = dst4[k];
        atomicAdd(&hist[dv.x >> SBSHIFT], 1);
        atomicAdd(&hist[dv.y >> SBSHIFT], 1);
        atomicAdd(&hist[dv.z >> SBSHIFT], 1);
        atomicAdd(&hist[dv.w >> SBSHIFT], 1);
    }
    if (tid < tail)
        atomicAdd(&hist[dst[c0 + (kn4 << 2) + tid] >> SBSHIFT], 1);
    __syncthreads();
    // exclusive scan of hist[0..256) on waves 0..3
    int h = 0, incl = 0;
    if (tid < 256) {
        h = hist[tid];
        incl = h;
        #pragma unroll
        for (int off = 1; off < 64; off <<= 1) {
            int t = __shfl_up(incl, off, 64);
            if (lane >= off) incl += t;
        }
        if (lane == 63) wsum[wid] = incl;
    }
    __syncthreads();
    if (tid < 256) {
        int pre = 0;
        for (int k = 0; k < wid; k++) pre += wsum[k];
        int e = pre + incl - h;
        base[tid] = e;
        cur[tid]  = e;
    }
    __syncthreads();
    // pass 2: scatter into LDS stage (edges L2-hot from pass 1)
    const int4* src4 = (const int4*)(src + c0);
    for (int k = tid; k < kn4; k += 512) {
        int4 dv = dst4[k];
        int4 sv = src4[k];
        int pos;
        pos = atomicAdd(&cur[dv.x >> SBSHIFT], 1);
        stage[pos] = ((dv.x & (SBROWS - 1)) << 17) | sv.x;
        pos = atomicAdd(&cur[dv.y >> SBSHIFT], 1);
        stage[pos] = ((dv.y & (SBROWS - 1)) << 17) | sv.y;
        pos = atomicAdd(&cur[dv.z >> SBSHIFT], 1);
        stage[pos] = ((dv.z & (SBROWS - 1)) << 17) | sv.z;
        pos = atomicAdd(&cur[dv.w >> SBSHIFT], 1);
        stage[pos] = ((dv.w & (SBROWS - 1)) << 17) | sv.w;
    }
    if (tid < tail) {
        int k = (kn4 << 2) + tid;
        int d = dst[c0 + k], s = src[c0 + k];
        int pos = atomicAdd(&cur[d >> SBSHIFT], 1);
        stage[pos] = ((d & (SBROWS - 1)) << 17) | s;
    }
    __syncthreads();
    // flush: fully coalesced linear copy, no padding, no partial lines
    for (int j = tid; j < kn; j += 512)
        slots_lin[c0 + j] = stage[j];
    if (tid < 256) cbase[blockIdx.x * 257 + tid] = base[tid];
    if (tid == 0)  cbase[blockIdx.x * 257 + 256] = kn;
}

// ---------- K3a: grid-parallel per-sb totals from cbase diffs ----------
__global__ void sbtot_kernel(const int* __restrict__ cbase,
                             int* __restrict__ sbtot, int NSB, int NCH) {
    __shared__ int wsum[4];
    const int s = blockIdx.x;
    const int tid = threadIdx.x;   // 256 (NCH <= 256)
    int v = 0;
    if (tid < NCH)
        v = cbase[tid * 257 + s + 1] - cbase[tid * 257 + s];
    #pragma unroll
    for (int off = 1; off < 64; off <<= 1) v += __shfl_xor(v, off, 64);
    if ((tid & 63) == 0) wsum[tid >> 6] = v;
    __syncthreads();
    if (tid == 0) sbtot[s] = wsum[0] + wsum[1] + wsum[2] + wsum[3];
}

// ---------- K3b: tiny 1-block scan of sbtot -> sb_base[NSB+1] ----------
__global__ void sb_scan2_kernel(const int* __restrict__ sbtot,
                                int* __restrict__ sb_base,
                                int* __restrict__ node_off,
                                int NSB, int n_nodes) {
    __shared__ int wsum[4];
    const int tid = threadIdx.x;   // 256 (NSB <= 256)
    int v = (tid < NSB) ? sbtot[tid] : 0;
    int incl = v;
    #pragma unroll
    for (int off = 1; off < 64; off <<= 1) {
        int t = __shfl_up(incl, off, 64);
        if ((tid & 63) >= off) incl += t;
    }
    if ((tid & 63) == 63) wsum[tid >> 6] = incl;
    __syncthreads();
    int pre = 0;
    for (int k = 0; k < (tid >> 6); k++) pre += wsum[k];
    if (tid < NSB) sb_base[tid] = pre + incl - v;
    if (tid == 0) {
        int g = wsum[0] + wsum[1] + wsum[2] + wsum[3];
        sb_base[NSB] = g;
        node_off[n_nodes] = g;
    }
}

// ---------- K4: per-sb LDS counting sort -> sorted2 (coalesced) + node_off ---
__global__ __launch_bounds__(512) void fine_sort_kernel(
        const int* __restrict__ slots_lin,
        const int* __restrict__ cbase,
        const int* __restrict__ sb_base,
        int* __restrict__ sorted2,
        int* __restrict__ node_off,
        int n_nodes, int NCH) {
    __shared__ int rstart[NCH_MAX], rc[NCH_MAX];
    __shared__ int counts[SBROWS], cur[SBROWS];
    __shared__ int wsum[8];
    __shared__ int stage_out[STAGE_CAP];   // 34.8 KB
    const int s = blockIdx.x;
    const int tid = threadIdx.x;           // 512
    const int wid = tid >> 6, lane = tid & 63;

    if (tid < NCH) {
        int a = cbase[tid * 257 + s];
        int b = cbase[tid * 257 + s + 1];
        rstart[tid] = tid * CHUNK_E + a;
        rc[tid] = b - a;
    }
    counts[tid] = 0;                       // 512 threads cover SBROWS exactly
    __syncthreads();
    const int sbb = sb_base[s];
    const int T   = sb_base[s + 1] - sbb;
    const bool fast = (T <= STAGE_CAP);
    // phase 1: histogram by local node
    for (int c = wid; c < NCH; c += 8) {
        int n = rc[c], st = rstart[c];
        for (int j = lane; j < n; j += 64)
            atomicAdd(&counts[((unsigned)slots_lin[st + j]) >> 17], 1);
    }
    __syncthreads();
    // phase 2: exclusive scan of counts[512], one element per thread
    int v = counts[tid];
    int incl = v;
    #pragma unroll
    for (int off = 1; off < 64; off <<= 1) {
        int t = __shfl_up(incl, off, 64);
        if (lane >= off) incl += t;
    }
    if (lane == 63) wsum[wid] = incl;
    __syncthreads();
    int pre = 0;
    for (int k = 0; k < wid; k++) pre += wsum[k];
    int e0 = pre + incl - v;
    cur[tid] = fast ? e0 : sbb + e0;
    int g0 = (s << SBSHIFT) + tid;
    if (g0 < n_nodes) node_off[g0] = sbb + e0;
    __syncthreads();
    // phase 3: scatter (LDS stage fast path; direct global on skewed sb)
    for (int c = wid; c < NCH; c += 8) {
        int n = rc[c], st = rstart[c];
        for (int j = lane; j < n; j += 64) {
            int pl = slots_lin[st + j];
            int r = ((unsigned)pl) >> 17;
            int pos = atomicAdd(&cur[r], 1);
            if (fast) stage_out[pos] = pl & 0x1FFFF;
            else      sorted2[pos]   = pl & 0x1FFFF;
        }
    }
    __syncthreads();
    // phase 4: coalesced flush
    if (fast) {
        for (int i = tid; i < T; i += 512)
            sorted2[sbb + i] = stage_out[i];
    }
}

// ---------- K5: wave per node; coalesced index preload + shfl broadcast; up to
//               4 row-gathers in flight per group (load phase separated from
//               accumulate phase so one vmcnt covers all 4). ----------
__global__ void gather_sum_kernel(const unsigned int* __restrict__ emb16,
                                  const int* __restrict__ sorted2,
                                  const int* __restrict__ node_off,
                                  float* __restrict__ out, int n_nodes) {
    int wave = (blockIdx.x * blockDim.x + threadIdx.x) >> 6;
    if (wave >= n_nodes) return;
    const int lane = threadIdx.x & 63;
    const int g = lane >> 3;          // 8 edge slots
    const int c = lane & 7;           // 8 int4-chunks per 128B row
    const int beg = node_off[wave], end = node_off[wave + 1];
    const int deg = end - beg;
    const int dmain = min(deg, 64);
    const int4* row = (const int4*)emb16;   // 8 int4 per row

    // one coalesced 64-lane load grabs this node's whole index list
    int myidx = 0;
    if (lane < dmain) myidx = __builtin_nontemporal_load(sorted2 + beg + lane);

    float acc[8] = {0.f, 0.f, 0.f, 0.f, 0.f, 0.f, 0.f, 0.f};

    for (int base = 0; base < dmain; base += 32) {
        const int m = dmain - base;   // edges remaining in this 32-round
        int s0 = __shfl(myidx, base + g, 64);
        int s1 = __shfl(myidx, base + g + 8, 64);
        int s2 = __shfl(myidx, base + g + 16, 64);
        int s3 = __shfl(myidx, base + g + 24, 64);
        int4 u0 = make_int4(0, 0, 0, 0);
        int4 u1 = make_int4(0, 0, 0, 0);
        int4 u2 = make_int4(0, 0, 0, 0);
        int4 u3 = make_int4(0, 0, 0, 0);
        // load phase: up to 4 independent gathers in flight per group
        if (g < m)      u0 = row[s0 * 8 + c];
        if (g + 8 < m)  u1 = row[s1 * 8 + c];
        if (g + 16 < m) u2 = row[s2 * 8 + c];
        if (g + 24 < m) u3 = row[s3 * 8 + c];
        // accumulate phase (zeros are numeric no-ops for masked slots)
        acc[0] += bl16(u0.x) + bl16(u1.x) + bl16(u2.x) + bl16(u3.x);
        acc[1] += bh16(u0.x) + bh16(u1.x) + bh16(u2.x) + bh16(u3.x);
        acc[2] += bl16(u0.y) + bl16(u1.y) + bl16(u2.y) + bl16(u3.y);
        acc[3] += bh16(u0.y) + bh16(u1.y) + bh16(u2.y) + bh16(u3.y);
        acc[4] += bl16(u0.z) + bl16(u1.z) + bl16(u2.z) + bl16(u3.z);
        acc[5] += bh16(u0.z) + bh16(u1.z) + bh16(u2.z) + bh16(u3.z);
        acc[6] += bl16(u0.w) + bl16(u1.w) + bl16(u2.w) + bl16(u3.w);
        acc[7] += bh16(u0.w) + bh16(u1.w) + bh16(u2.w) + bh16(u3.w);
    }
    // rare tail: deg > 64
    for (int e = beg + 64 + g; e < end; e += 8) {
        int s0 = __builtin_nontemporal_load(sorted2 + e);
        int4 u0 = row[s0 * 8 + c];
        acc[0] += bl16(u0.x); acc[1] += bh16(u0.x);
        acc[2] += bl16(u0.y); acc[3] += bh16(u0.y);
        acc[4] += bl16(u0.z); acc[5] += bh16(u0.z);
        acc[6] += bl16(u0.w); acc[7] += bh16(u0.w);
    }
    #pragma unroll
    for (int off = 8; off <= 32; off <<= 1) {
        #pragma unroll
        for (int k = 0; k < 8; k++) acc[k] += __shfl_xor(acc[k], off, 64);
    }
    if (g == 0) {
        f32x4* out4 = (f32x4*)out;
        f32x4 o0 = {acc[0], acc[1], acc[2], acc[3]};
        f32x4 o1 = {acc[4], acc[5], acc[6], acc[7]};
        __builtin_nontemporal_store(o0, out4 + wave * D4 + c * 2);
        __builtin_nontemporal_store(o1, out4 + wave * D4 + c * 2 + 1);
    }
}

// ---------- Fallback: atomic scatter ----------
__global__ void zero_out_kernel(float* __restrict__ out, int total4) {
    int i = blockIdx.x * blockDim.x + threadIdx.x;
    if (i < total4) ((float4*)out)[i] = make_float4(0.f, 0.f, 0.f, 0.f);
}

__global__ void scatter_fused_kernel(const float* __restrict__ x,
                                     const float* __restrict__ w,
                                     const int* __restrict__ src,
                                     const int* __restrict__ dst,
                                     float* __restrict__ out, int n_edges) {
    int t = blockIdx.x * blockDim.x + threadIdx.x;
    int e = t >> 4;
    int c = t & 15;
    if (e >= n_edges) return;
    int s = src[e];
    int d = dst[e];
    float4 xv = ((const float4*)x)[s * D4 + c];
    float4 wv = ((const float4*)w)[c];
    float* o = out + d * D + c * 4;
    unsafeAtomicAdd(o + 0, elu1(xv.x * wv.x));
    unsafeAtomicAdd(o + 1, elu1(xv.y * wv.y));
    unsafeAtomicAdd(o + 2, elu1(xv.z * wv.z));
    unsafeAtomicAdd(o + 3, elu1(xv.w * wv.w));
}

extern "C" void kernel_launch(void* const* d_in, const int* in_sizes, int n_in,
                              void* d_out, int out_size, void* d_ws, size_t ws_size,
                              hipStream_t stream) {
    const float* x   = (const float*)d_in[0];   // [N, 64] fp32
    const float* w   = (const float*)d_in[1];   // [1, 64] fp32
    const int*   src = (const int*)d_in[2];     // [E] int32
    const int*   dst = (const int*)d_in[3];     // [E] int32
    float* out = (float*)d_out;

    const int n_nodes = in_sizes[0] / D;
    const int n_edges = in_sizes[2];
    const int total4  = n_nodes * D4;
    const int total8  = n_nodes * 8;
    const int block = 256;

    const int NSB = (n_nodes + SBROWS - 1) >> SBSHIFT;
    const int NCH = (n_edges + CHUNK_E - 1) / CHUNK_E;

    auto align16 = [](size_t v) { return (v + 15) & ~size_t(15); };
    const size_t emb_b      = align16((size_t)n_nodes * D * 2);          // bf16
    const size_t slots_b    = align16((size_t)NCH * CHUNK_E * 4);
    const size_t cbase_b    = align16((size_t)NCH * 257 * 4);
    const size_t sbtot_b    = align16((size_t)NSB * 4);
    const size_t sbbase_b   = align16((size_t)(NSB + 1) * 4);
    const size_t sorted2_b  = align16((size_t)n_edges * 4);
    const size_t nodeoff_b  = align16((size_t)(n_nodes + 1) * 4);
    const size_t need = emb_b + slots_b + cbase_b + sbtot_b + sbbase_b +
                        sorted2_b + nodeoff_b;

    if (ws_size >= need && n_nodes <= 131072 && NSB <= NSB_MAX && NCH <= NCH_MAX) {
        char* p = (char*)d_ws;
        unsigned int* emb16 = (unsigned int*)p;  p += emb_b;
        int* slots_lin = (int*)p;  p += slots_b;
        int* cbase     = (int*)p;  p += cbase_b;
        int* sbtot     = (int*)p;  p += sbtot_b;
        int* sb_base   = (int*)p;  p += sbbase_b;
        int* sorted2   = (int*)p;  p += sorted2_b;
        int* node_off  = (int*)p;

        emb_kernel<<<(total8 + block - 1) / block, block, 0, stream>>>(
            x, w, (uint4*)emb16, total8);
        chunk_sort_kernel<<<NCH, 512, 0, stream>>>(
            src, dst, slots_lin, cbase, n_edges);
        sbtot_kernel<<<NSB, 256, 0, stream>>>(cbase, sbtot, NSB, NCH);
        sb_scan2_kernel<<<1, 256, 0, stream>>>(sbtot, sb_base, node_off,
                                               NSB, n_nodes);
        fine_sort_kernel<<<NSB, 512, 0, stream>>>(
            slots_lin, cbase, sb_base, sorted2, node_off, n_nodes, NCH);
        const int wave_blocks = (n_nodes * 64 + block - 1) / block;
        gather_sum_kernel<<<wave_blocks, block, 0, stream>>>(
            emb16, sorted2, node_off, out, n_nodes);
    } else {
        zero_out_kernel<<<(total4 + block - 1) / block, block, 0, stream>>>(out, total4);
        const int nt = n_edges * 16;
        scatter_fused_kernel<<<(nt + block - 1) / block, block, 0, stream>>>(
            x, w, src, dst, out, n_edges);
    }
}